// Round 10
// baseline (180.241 us; speedup 1.0000x reference)
//
#include <hip/hip_runtime.h>
#include <math.h>

#define NRAYS 8192
#define T 128
#define H 128
#define SHD 16

using short8 = __attribute__((ext_vector_type(8))) short;
using f32x4  = __attribute__((ext_vector_type(4))) float;
using f32x2  = __attribute__((ext_vector_type(2))) float;

__device__ __forceinline__ float fexp(float x) {
  return exp2f(x * 1.44269504088896341f);
}
__device__ __forceinline__ float softplus_f(float x) {
  return fmaxf(x, 0.f) + 0.693147180559945309f * log2f(1.f + fexp(-fabsf(x)));
}
__device__ __forceinline__ float sigmoid_f(float x) {
  return __builtin_amdgcn_rcpf(1.f + fexp(-x));
}

// RNE float->bf16 (preprocess only)
__device__ __forceinline__ unsigned f2bf(float f) {
  unsigned u = __float_as_uint(f);
  return (u + 0x7fffu + ((u >> 16) & 1u)) >> 16;
}

// RNE bf16 pack of a float pair: single VALU op (v_cvt_pk_bf16_f32, gfx950)
__device__ __forceinline__ unsigned pk2(f32x2 h) {
  unsigned r;
  asm("v_cvt_pk_bf16_f32 %0, %1, %2" : "=v"(r) : "v"(h[0]), "v"(h[1]));
  return r;
}

__device__ __forceinline__ float rflf(float v) {
  return __builtin_bit_cast(float, __builtin_amdgcn_readfirstlane(__builtin_bit_cast(int, v)));
}

// cross-lane gather: byteaddr = src_lane*4; lane crossbar (LDS pipe)
__device__ __forceinline__ float bpermf(int byteaddr, float v) {
  return __builtin_bit_cast(float, __builtin_amdgcn_ds_bpermute(byteaddr, __builtin_bit_cast(int, v)));
}

// DPP row_shr:N add-scan step on the VALU pipe (invalid lanes contribute 0)
template<int N>
__device__ __forceinline__ float dpp_shr0(float v) {
  return __builtin_bit_cast(float,
    __builtin_amdgcn_update_dpp(0, __builtin_bit_cast(int, v),
                                0x110 | N, 0xf, 0xf, false));
}
// 16-lane inclusive scan, pure VALU (replaces 4 shfl_up LDS ops)
__device__ __forceinline__ float scan16(float v) {
  v += dpp_shr0<1>(v);
  v += dpp_shr0<2>(v);
  v += dpp_shr0<4>(v);
  v += dpp_shr0<8>(v);
  return v;
}
__device__ __forceinline__ float readlane15f(float v) {
  return __builtin_bit_cast(float,
    __builtin_amdgcn_readlane(__builtin_bit_cast(int, v), 15));
}

// relu+bf16-pack an A-frag half-row pair set into a uint4
__device__ __forceinline__ uint4 build_frag(f32x2 tz,
    f32x2 b01, f32x2 b23, f32x2 b45, f32x2 b67,
    f32x2 s01, f32x2 s23, f32x2 s45, f32x2 s67) {
  const f32x2 zero2 = {0.f, 0.f};
  const f32x2 a01 = __builtin_elementwise_max(__builtin_elementwise_fma(tz, s01, b01), zero2);
  const f32x2 a23 = __builtin_elementwise_max(__builtin_elementwise_fma(tz, s23, b23), zero2);
  const f32x2 a45 = __builtin_elementwise_max(__builtin_elementwise_fma(tz, s45, b45), zero2);
  const f32x2 a67 = __builtin_elementwise_max(__builtin_elementwise_fma(tz, s67, b67), zero2);
  return make_uint4(pk2(a01), pk2(a23), pk2(a45), pk2(a67));
}

// ---- preprocess (unchanged from R8) ----
__global__ void preprocess(const float* __restrict__ W2, const float* __restrict__ Wd,
                           const float* __restrict__ Wc, const float* __restrict__ bc,
                           const float* __restrict__ origins, const float* __restrict__ dirs,
                           const float* __restrict__ W1, const float* __restrict__ b1,
                           unsigned short* __restrict__ w2t,
                           unsigned short* __restrict__ woutf,
                           float* __restrict__ rayp_all,
                           float* __restrict__ bs_all) {
  const int t = blockIdx.x * 256 + threadIdx.x;
  if (t < 16384) {
    const int n = t >> 7, p = t & 127;
    const int o = (p >> 3) ^ (n & 7);
    const int k = o * 8 + (p & 7);
    w2t[t] = (unsigned short)f2bf(W2[k * 128 + n]);
  }
  if (t < 2048) {
    const int kk = t >> 9, L = (t >> 3) & 63, j = t & 7;
    const int c = L & 15, g = L >> 4;
    const int k = kk * 32 + g * 8 + j;
    float v = 0.f;
    if (c == 0) v = Wd[k];
    else if (c < 4) v = Wc[k * 3 + (c - 1)];
    woutf[t] = (unsigned short)f2bf(v);
  }
  if (t < NRAYS) {
    const float ox = origins[t*3+0], oy = origins[t*3+1], oz = origins[t*3+2];
    const float dx = dirs[t*3+0],  dy = dirs[t*3+1],  dz = dirs[t*3+2];
    const float ix = 1.f/dx, iy = 1.f/dy, iz = 1.f/dz;
    const float t1x = (-1.f-ox)*ix, t2x = (1.f-ox)*ix;
    const float t1y = (-1.f-oy)*iy, t2y = (1.f-oy)*iy;
    const float t1z = (-1.f-oz)*iz, t2z = (1.f-oz)*iz;
    float tnear = fmaxf(fmaxf(fminf(t1x,t2x), fminf(t1y,t2y)), fminf(t1z,t2z));
    tnear = fmaxf(tnear, 0.f);
    const float tfar = fminf(fminf(fmaxf(t1x,t2x), fmaxf(t1y,t2y)), fmaxf(t1z,t2z));
    const bool  active = tfar > tnear;
    const float tfar_c = fmaxf(tfar, tnear + 1e-3f);
    const float dnorm = sqrtf(dx*dx + dy*dy + dz*dz);
    const float nx = dx/dnorm, ny = dy/dnorm, nz = dz/dnorm;
    const float x2 = nx*nx, y2 = ny*ny, z2 = nz*nz;
    const float xy = nx*ny, yz = ny*nz, xz = nx*nz;
    float ynm[16];
    ynm[0]  = 0.282094791773878f;
    ynm[1]  = -0.48860251190292f*ny;
    ynm[2]  = 0.48860251190292f*nz;
    ynm[3]  = -0.48860251190292f*nx;
    ynm[4]  = 1.0925484305920792f*xy;
    ynm[5]  = -1.0925484305920792f*yz;
    ynm[6]  = 0.94617469575756f*z2 - 0.31539156525252f;
    ynm[7]  = -1.0925484305920792f*xz;
    ynm[8]  = 0.5462742152960396f*(x2-y2);
    ynm[9]  = 0.5900435899266435f*ny*(-3.f*x2+y2);
    ynm[10] = 2.8906114426405538f*xy*nz;
    ynm[11] = 0.4570457994644658f*ny*(1.f-5.f*z2);
    ynm[12] = 0.3731763325901154f*nz*(5.f*z2-3.f);
    ynm[13] = 0.4570457994644658f*nx*(1.f-5.f*z2);
    ynm[14] = 1.445305721320277f*nz*(x2-y2);
    ynm[15] = 0.5900435899266435f*nx*(-x2+3.f*y2);
    float cp0 = bc[0], cp1 = bc[1], cp2 = bc[2];
    #pragma unroll
    for (int s = 0; s < SHD; ++s) {
      cp0 = fmaf(ynm[s], Wc[(H+s)*3+0], cp0);
      cp1 = fmaf(ynm[s], Wc[(H+s)*3+1], cp1);
      cp2 = fmaf(ynm[s], Wc[(H+s)*3+2], cp2);
    }
    rayp_all[t*8+0] = tfar_c;
    rayp_all[t*8+1] = dnorm;
    rayp_all[t*8+2] = active ? 1.f : 0.f;
    rayp_all[t*8+3] = cp0;
    rayp_all[t*8+4] = cp1;
    rayp_all[t*8+5] = cp2;
    rayp_all[t*8+6] = tnear;
    rayp_all[t*8+7] = 0.f;

    float* bp = bs_all + t * 256;
    #pragma unroll 4
    for (int uu = 0; uu < 128; uu += 4) {
      const float4 w0r = *(const float4*)&W1[uu];
      const float4 w1r = *(const float4*)&W1[128 + uu];
      const float4 w2r = *(const float4*)&W1[256 + uu];
      const float4 bb  = *(const float4*)&b1[uu];
      float4 bo, so;
      bo.x = fmaf(ox, w0r.x, fmaf(oy, w1r.x, fmaf(oz, w2r.x, bb.x)));
      bo.y = fmaf(ox, w0r.y, fmaf(oy, w1r.y, fmaf(oz, w2r.y, bb.y)));
      bo.z = fmaf(ox, w0r.z, fmaf(oy, w1r.z, fmaf(oz, w2r.z, bb.z)));
      bo.w = fmaf(ox, w0r.w, fmaf(oy, w1r.w, fmaf(oz, w2r.w, bb.w)));
      so.x = fmaf(dx, w0r.x, fmaf(dy, w1r.x, dz * w2r.x));
      so.y = fmaf(dx, w0r.y, fmaf(dy, w1r.y, dz * w2r.y));
      so.z = fmaf(dx, w0r.z, fmaf(dy, w1r.z, dz * w2r.z));
      so.w = fmaf(dx, w0r.w, fmaf(dy, w1r.w, dz * w2r.w));
      *(float4*)&bp[uu]       = bo;
      *(float4*)&bp[128 + uu] = so;
    }
  }
}

// 4 rays per block, ONE WAVE PER RAY. R8 post-mortem: LDS pipe is the floor
// (~3100 cyc/wave; wf re-reads = half of it); occupancy 2->3 waves/SIMD gave
// only +4%. THIS ROUND attacks the LDS pipe:
//  (a) 64-sample passes: acc[4][8] (128 AGPR) -> each W2 fragment ds_read
//      feeds 4 MFMAs instead of 2 -> wf reads 128->64/wave; b2-init 32->16.
//  (b) transmittance scans via DPP row_shr (VALU pipe) + readlane broadcasts
//      (csum becomes scalar) -> removes all scan shfl LDS traffic.
// Est. LDS 3100 -> ~1900 cyc/wave (floor 41 -> ~25 us).
// launch_bounds(256,2): need ~235 regs (128 AGPR + ~105 VGPR) under the
// honest 256 budget (R5-proven). Occupancy 2 waves/SIMD - intentional.
// Tripwire: WRITE_SIZE must stay ~9.5 MB (benign bs_all writeback); >>20 MB
// means acc widening spilled -> fall back to 48-sample passes.
__global__ __launch_bounds__(256, 2) void nerf_render(
    const float* __restrict__ origins, const float* __restrict__ dirs,
    const float* __restrict__ u, const float* __restrict__ b2,
    const float* __restrict__ bd, const unsigned short* __restrict__ w2t,
    const unsigned short* __restrict__ woutf, const float* __restrict__ rayp_all,
    const float* __restrict__ bs_all, float* __restrict__ out)
{
  const int tid = threadIdx.x;
  const int L = tid & 63;
  const int w = tid >> 6;
  const int g = L >> 4;
  const int c = L & 15;
  const int ray = blockIdx.x * 4 + w;

  __shared__ __align__(16) short Bs[16384];     // swizzled W2^T (shared by all 4 waves)
  __shared__ __align__(16) float b2s[128];      // b2 (acc re-init each half)
  __shared__ __align__(16) short As2[4 * 640];  // per-wave epilogue slab

  // ---- stage W2 + b2 (cooperative, the ONLY barrier) ----
  {
    const float4* src = (const float4*)w2t;
    float4* dst = (float4*)Bs;
    #pragma unroll
    for (int i = 0; i < 8; ++i) dst[tid + i * 256] = src[tid + i * 256];
  }
  if (tid < 128) b2s[tid] = b2[tid];

  // ---- per-ray scalars -> SGPR (wave-uniform) ----
  const float tfar_c = rflf(rayp_all[ray*8+0]);
  const float dnorm  = rflf(rayp_all[ray*8+1]);
  const float actf   = rflf(rayp_all[ray*8+2]);
  const float cp0    = rflf(rayp_all[ray*8+3]);
  const float cp1    = rflf(rayp_all[ray*8+4]);
  const float cp2    = rflf(rayp_all[ray*8+5]);
  const float tnear  = rflf(rayp_all[ray*8+6]);
  const float bd0    = rflf(bd[0]);
  const float ox = rflf(origins[ray*3+0]);
  const float oy = rflf(origins[ray*3+1]);
  const float oz = rflf(origins[ray*3+2]);
  const float dx = rflf(dirs[ray*3+0]);
  const float dy = rflf(dirs[ray*3+1]);
  const float dz = rflf(dirs[ray*3+2]);
  const bool active = actf != 0.f;

  // ---- per-sample setup in registers: lane L holds samples L and 64+L ----
  float ts_q[2], dmn_q[2];
  #pragma unroll
  for (int q = 0; q < 2; ++q) {
    const int s = q*64 + L;
    const float uv = u[ray*T + s];
    const float frac = ((float)s + uv) * (1.f/(float)T);
    const float tt = fmaf(tfar_c - tnear, frac, tnear);
    ts_q[q] = tt;
    const float px = fmaf(dx, tt, ox);
    const float py = fmaf(dy, tt, oy);
    const float pz = fmaf(dz, tt, oz);
    dmn_q[q] = ((fabsf(px) <= 1.f) && (fabsf(py) <= 1.f) && (fabsf(pz) <= 1.f) && active)
                ? 1.f : 0.f;
  }
  {
    const float t64 = __shfl(ts_q[1], 0);
    float tn0 = __shfl(ts_q[0], (L+1) & 63);
    float tn1 = __shfl(ts_q[1], (L+1) & 63);
    tn0 = (L == 63) ? t64 : tn0;
    tn1 = (L == 63) ? tfar_c * 10.f : tn1;
    dmn_q[0] = dmn_q[0] * (tn0 - ts_q[0]) * dnorm;   // mask*delta*dnorm
    dmn_q[1] = dmn_q[1] * (tn1 - ts_q[1]) * dnorm;
  }

  // epilogue A-frags (global, L2-hot)
  short8 wa[4];
  #pragma unroll
  for (int kk = 0; kk < 4; ++kk)
    wa[kk] = *(const short8*)&woutf[(kk*64 + L)*8];

  __syncthreads();   // Bs/b2s ready; waves fully independent from here on

  short* As2w = As2 + w * 640;
  const f32x2 zero2 = {0.f, 0.f};
  f32x4 acc[4][8];                 // 64 samples x 128 units (128 AGPR)
  float csum = 0.f;                // wave-uniform (scalar via readlane)
  float pw = 0.f, pxc = 0.f, pyc = 0.f, pzc = 0.f;

  #pragma unroll
  for (int half = 0; half < 2; ++half) {
    // ---- per-sample t / (mask*delta*dnorm) for 4 16-sample groups ----
    float t_[4], d_[4];
    #pragma unroll
    for (int tm = 0; tm < 4; ++tm) {
      const int idx = (tm*16 + c) * 4;
      t_[tm] = bpermf(idx, ts_q[half]);
      d_[tm] = bpermf(idx, dmn_q[half]);
    }

    // acc init = b2 (broadcast ds_read_b128, shared by 4 tm)
    #pragma unroll
    for (int mt = 0; mt < 8; ++mt) {
      const f32x4 bv = *(const f32x4*)&b2s[mt*16 + g*4];
      acc[0][mt] = bv; acc[1][mt] = bv; acc[2][mt] = bv; acc[3][mt] = bv;
    }

    // per-half laundered pointer (prevents cross-half reg pinning)
    const float* bsp = bs_all + ray*256;
    asm("" : "+v"(bsp));

    // ---- fused affine-layer1 + layer2 MFMA: each wf read feeds 4 MFMAs ----
    #pragma unroll
    for (int ks = 0; ks < 4; ++ks) {
      const f32x4 bq0 = *(const f32x4*)&bsp[ks*32 + g*8];
      const f32x4 bq1 = *(const f32x4*)&bsp[ks*32 + g*8 + 4];
      const f32x4 sq0 = *(const f32x4*)&bsp[128 + ks*32 + g*8];
      const f32x4 sq1 = *(const f32x4*)&bsp[128 + ks*32 + g*8 + 4];
      const f32x2 b01 = {bq0[0], bq0[1]}, b23 = {bq0[2], bq0[3]};
      const f32x2 b45 = {bq1[0], bq1[1]}, b67 = {bq1[2], bq1[3]};
      const f32x2 s01 = {sq0[0], sq0[1]}, s23 = {sq0[2], sq0[3]};
      const f32x2 s45 = {sq1[0], sq1[1]}, s67 = {sq1[2], sq1[3]};
      union U { uint4 u; short8 s; } A0, A1, A2, A3;
      A0.u = build_frag((f32x2){t_[0], t_[0]}, b01,b23,b45,b67, s01,s23,s45,s67);
      A1.u = build_frag((f32x2){t_[1], t_[1]}, b01,b23,b45,b67, s01,s23,s45,s67);
      A2.u = build_frag((f32x2){t_[2], t_[2]}, b01,b23,b45,b67, s01,s23,s45,s67);
      A3.u = build_frag((f32x2){t_[3], t_[3]}, b01,b23,b45,b67, s01,s23,s45,s67);
      const int swb = ((ks*4 + g) ^ (c & 7)) * 8;   // swizzled octet (proven)
      #pragma unroll
      for (int mt = 0; mt < 8; ++mt) {
        const short8 wf = *(const short8*)&Bs[(mt*16 + c)*128 + swb];
        acc[0][mt] = __builtin_amdgcn_mfma_f32_16x16x32_bf16(wf, A0.s, acc[0][mt], 0, 0, 0);
        acc[1][mt] = __builtin_amdgcn_mfma_f32_16x16x32_bf16(wf, A1.s, acc[1][mt], 0, 0, 0);
        acc[2][mt] = __builtin_amdgcn_mfma_f32_16x16x32_bf16(wf, A2.s, acc[2][mt], 0, 0, 0);
        acc[3][mt] = __builtin_amdgcn_mfma_f32_16x16x32_bf16(wf, A3.s, acc[3][mt], 0, 0, 0);
      }
    }

    // ---- epilogue: relu -> bf16 slab -> 4-k-step MFMA dot with Wout ----
    f32x4 osig[4];
    #pragma unroll
    for (int tm = 0; tm < 4; ++tm) {
      f32x4 oacc;
      oacc[0] = 0.f; oacc[1] = 0.f; oacc[2] = 0.f; oacc[3] = 0.f;
      #pragma unroll
      for (int kk = 0; kk < 4; ++kk) {
        #pragma unroll
        for (int i = 0; i < 2; ++i) {
          const f32x4 a = acc[tm][kk*2 + i];
          const f32x2 h01 = __builtin_elementwise_max((f32x2){a[0], a[1]}, zero2);
          const f32x2 h23 = __builtin_elementwise_max((f32x2){a[2], a[3]}, zero2);
          *(uint2*)&As2w[c*40 + i*16 + g*4] = make_uint2(pk2(h01), pk2(h23));
        }
        const short8 hbf = *(const short8*)&As2w[c*40 + g*8];
        oacc = __builtin_amdgcn_mfma_f32_16x16x32_bf16(wa[kk], hbf, oacc, 0, 0, 0);
      }
      osig[tm] = oacc;   // lanes g==0: {sigma_pre, c0, c1, c2}
    }

    // ---- online transmittance, 64 samples (valid in lanes 0..15) ----
    float sd[4], ptm[4];
    #pragma unroll
    for (int tm = 0; tm < 4; ++tm)
      sd[tm] = softplus_f(osig[tm][0] + bd0) * d_[tm];
    float tot[4];
    #pragma unroll
    for (int tm = 0; tm < 4; ++tm) {
      ptm[tm] = scan16(sd[tm]);          // VALU (DPP), not LDS
      tot[tm] = readlane15f(ptm[tm]);    // scalar broadcast
    }
    const float o1 = tot[0];
    const float o2 = o1 + tot[1];
    const float o3 = o2 + tot[2];
    const float cs0 = csum + ptm[0];
    const float cs1 = csum + o1 + ptm[1];
    const float cs2 = csum + o2 + ptm[2];
    const float cs3 = csum + o3 + ptm[3];
    csum += o3 + tot[3];
    const float w0 = fexp(sd[0] - cs0) - fexp(-cs0);   // == 0 when sd == 0
    const float w1 = fexp(sd[1] - cs1) - fexp(-cs1);
    const float w2 = fexp(sd[2] - cs2) - fexp(-cs2);
    const float w3 = fexp(sd[3] - cs3) - fexp(-cs3);
    pw  += w0 + w1 + w2 + w3;
    pxc += w0 * sigmoid_f(osig[0][1] + cp0) + w1 * sigmoid_f(osig[1][1] + cp0)
         + w2 * sigmoid_f(osig[2][1] + cp0) + w3 * sigmoid_f(osig[3][1] + cp0);
    pyc += w0 * sigmoid_f(osig[0][2] + cp1) + w1 * sigmoid_f(osig[1][2] + cp1)
         + w2 * sigmoid_f(osig[2][2] + cp1) + w3 * sigmoid_f(osig[3][2] + cp1);
    pzc += w0 * sigmoid_f(osig[0][3] + cp2) + w1 * sigmoid_f(osig[1][3] + cp2)
         + w2 * sigmoid_f(osig[2][3] + cp2) + w3 * sigmoid_f(osig[3][3] + cp2);
  }

  // ---- per-ray reduction over lanes 0..15, store from lane 0 ----
  #pragma unroll
  for (int off = 1; off < 16; off <<= 1) {
    pw  += __shfl_xor(pw, off);
    pxc += __shfl_xor(pxc, off);
    pyc += __shfl_xor(pyc, off);
    pzc += __shfl_xor(pzc, off);
  }
  if (L == 0) {
    float4 o;
    o.x = active ? pxc : 0.f;
    o.y = active ? pyc : 0.f;
    o.z = active ? pzc : 0.f;
    o.w = active ? pw  : 0.f;
    *(float4*)&out[ray*4] = o;
  }
}

extern "C" void kernel_launch(void* const* d_in, const int* in_sizes, int n_in,
                              void* d_out, int out_size, void* d_ws, size_t ws_size,
                              hipStream_t stream) {
  const float* origins = (const float*)d_in[0];
  const float* dirs    = (const float*)d_in[1];
  const float* u       = (const float*)d_in[2];
  const float* W1      = (const float*)d_in[3];
  const float* b1      = (const float*)d_in[4];
  const float* W2      = (const float*)d_in[5];
  const float* b2      = (const float*)d_in[6];
  const float* Wd      = (const float*)d_in[7];
  const float* bd      = (const float*)d_in[8];
  const float* Wc      = (const float*)d_in[9];
  const float* bc      = (const float*)d_in[10];

  unsigned short* w2t      = (unsigned short*)d_ws;
  unsigned short* woutf    = (unsigned short*)((char*)d_ws + 32768);
  float*          rayp_all = (float*)((char*)d_ws + 36864);     // 8192*8*4 = 262144 B
  float*          bs_all   = (float*)((char*)d_ws + 299008);    // 8192*256*4 = 8 MB

  preprocess<<<64, 256, 0, stream>>>(W2, Wd, Wc, bc, origins, dirs, W1, b1,
                                     w2t, woutf, rayp_all, bs_all);
  nerf_render<<<NRAYS/4, 256, 0, stream>>>(origins, dirs, u, b2, bd,
                                           w2t, woutf, rayp_all, bs_all,
                                           (float*)d_out);
}

// Round 11
// 132.297 us; speedup vs baseline: 1.3624x; 1.3624x over previous
//
#include <hip/hip_runtime.h>
#include <math.h>

#define NRAYS 8192
#define T 128
#define H 128
#define SHD 16

using short8 = __attribute__((ext_vector_type(8))) short;
using f32x4  = __attribute__((ext_vector_type(4))) float;
using f32x2  = __attribute__((ext_vector_type(2))) float;

__device__ __forceinline__ float fexp(float x) {
  return exp2f(x * 1.44269504088896341f);
}
__device__ __forceinline__ float softplus_f(float x) {
  return fmaxf(x, 0.f) + 0.693147180559945309f * log2f(1.f + fexp(-fabsf(x)));
}
__device__ __forceinline__ float sigmoid_f(float x) {
  return __builtin_amdgcn_rcpf(1.f + fexp(-x));
}

// RNE float->bf16 (preprocess only)
__device__ __forceinline__ unsigned f2bf(float f) {
  unsigned u = __float_as_uint(f);
  return (u + 0x7fffu + ((u >> 16) & 1u)) >> 16;
}

// RNE bf16 pack of a float pair: single VALU op (v_cvt_pk_bf16_f32, gfx950)
__device__ __forceinline__ unsigned pk2(f32x2 h) {
  unsigned r;
  asm("v_cvt_pk_bf16_f32 %0, %1, %2" : "=v"(r) : "v"(h[0]), "v"(h[1]));
  return r;
}

// ---- preprocess (R1 version — cheap; R8's bs_all variant cost +40us scored
// because only 32 blocks carried the per-ray coefficient work) ----
// w2t: bf16 W2^T, XOR-swizzled: w2t[n*128 + p], octet o=(p>>3)^(n&7), k=o*8+(p&7)
// woutf[(kk*64+L)*8+j]: epilogue A-frag; rayp_all[r][8] = AABB + SH scalars.
__global__ void preprocess(const float* __restrict__ W2, const float* __restrict__ Wd,
                           const float* __restrict__ Wc, const float* __restrict__ bc,
                           const float* __restrict__ origins, const float* __restrict__ dirs,
                           unsigned short* __restrict__ w2t,
                           unsigned short* __restrict__ woutf,
                           float* __restrict__ rayp_all) {
  const int t = blockIdx.x * 256 + threadIdx.x;
  if (t < 16384) {
    const int n = t >> 7, p = t & 127;
    const int o = (p >> 3) ^ (n & 7);
    const int k = o * 8 + (p & 7);
    w2t[t] = (unsigned short)f2bf(W2[k * 128 + n]);
  }
  if (t < 2048) {
    const int kk = t >> 9, L = (t >> 3) & 63, j = t & 7;
    const int c = L & 15, g = L >> 4;
    const int k = kk * 32 + g * 8 + j;
    float v = 0.f;
    if (c == 0) v = Wd[k];
    else if (c < 4) v = Wc[k * 3 + (c - 1)];
    woutf[t] = (unsigned short)f2bf(v);
  }
  if (t < NRAYS) {
    const float ox = origins[t*3+0], oy = origins[t*3+1], oz = origins[t*3+2];
    const float dx = dirs[t*3+0],  dy = dirs[t*3+1],  dz = dirs[t*3+2];
    const float ix = 1.f/dx, iy = 1.f/dy, iz = 1.f/dz;
    const float t1x = (-1.f-ox)*ix, t2x = (1.f-ox)*ix;
    const float t1y = (-1.f-oy)*iy, t2y = (1.f-oy)*iy;
    const float t1z = (-1.f-oz)*iz, t2z = (1.f-oz)*iz;
    float tnear = fmaxf(fmaxf(fminf(t1x,t2x), fminf(t1y,t2y)), fminf(t1z,t2z));
    tnear = fmaxf(tnear, 0.f);
    const float tfar = fminf(fminf(fmaxf(t1x,t2x), fmaxf(t1y,t2y)), fmaxf(t1z,t2z));
    const bool  active = tfar > tnear;
    const float tfar_c = fmaxf(tfar, tnear + 1e-3f);
    const float dnorm = sqrtf(dx*dx + dy*dy + dz*dz);
    const float nx = dx/dnorm, ny = dy/dnorm, nz = dz/dnorm;
    const float x2 = nx*nx, y2 = ny*ny, z2 = nz*nz;
    const float xy = nx*ny, yz = ny*nz, xz = nx*nz;
    float ynm[16];
    ynm[0]  = 0.282094791773878f;
    ynm[1]  = -0.48860251190292f*ny;
    ynm[2]  = 0.48860251190292f*nz;
    ynm[3]  = -0.48860251190292f*nx;
    ynm[4]  = 1.0925484305920792f*xy;
    ynm[5]  = -1.0925484305920792f*yz;
    ynm[6]  = 0.94617469575756f*z2 - 0.31539156525252f;
    ynm[7]  = -1.0925484305920792f*xz;
    ynm[8]  = 0.5462742152960396f*(x2-y2);
    ynm[9]  = 0.5900435899266435f*ny*(-3.f*x2+y2);
    ynm[10] = 2.8906114426405538f*xy*nz;
    ynm[11] = 0.4570457994644658f*ny*(1.f-5.f*z2);
    ynm[12] = 0.3731763325901154f*nz*(5.f*z2-3.f);
    ynm[13] = 0.4570457994644658f*nx*(1.f-5.f*z2);
    ynm[14] = 1.445305721320277f*nz*(x2-y2);
    ynm[15] = 0.5900435899266435f*nx*(-x2+3.f*y2);
    float cp0 = bc[0], cp1 = bc[1], cp2 = bc[2];
    #pragma unroll
    for (int s = 0; s < SHD; ++s) {
      cp0 = fmaf(ynm[s], Wc[(H+s)*3+0], cp0);
      cp1 = fmaf(ynm[s], Wc[(H+s)*3+1], cp1);
      cp2 = fmaf(ynm[s], Wc[(H+s)*3+2], cp2);
    }
    rayp_all[t*8+0] = tfar_c;
    rayp_all[t*8+1] = dnorm;
    rayp_all[t*8+2] = active ? 1.f : 0.f;
    rayp_all[t*8+3] = cp0;
    rayp_all[t*8+4] = cp1;
    rayp_all[t*8+5] = cp2;
    rayp_all[t*8+6] = tnear;
    rayp_all[t*8+7] = 0.f;
  }
}

// One ray per block; wave w owns samples [32w, 32w+32) — the R1 structure
// (best scored: 133.2us). R10 post-mortem: all throughput knobs (occupancy,
// LDS op count, VALU count) measured-null on the one-wave-per-ray variants;
// reverting to this base. NEW this round: the epilogue slab was REUSED across
// kk (WAR hazard -> write(kk)/read(kk)/write(kk+1) serialize through the
// in-order LDS pipe, chained with the serial oacc MFMA accumulation).
// Slab is now PER-KK DISJOINT (4x area, still inside dead Bs space — zero
// LDS cost) and all 8 writes per tm issue before any read: writes/reads
// pipeline instead of serializing.
// LDS: Bs 32768 + baseA/slopeA 1024 + ts/mask 1024 + wred/wtot ~40 = 35328.
__global__ __launch_bounds__(256, 4) void nerf_render(
    const float* __restrict__ origins, const float* __restrict__ dirs,
    const float* __restrict__ u, const float* __restrict__ W1,
    const float* __restrict__ b1, const float* __restrict__ b2,
    const float* __restrict__ bd, const unsigned short* __restrict__ w2t,
    const unsigned short* __restrict__ woutf, const float* __restrict__ rayp_all,
    float* __restrict__ out)
{
  const int ray = blockIdx.x;
  const int tid = threadIdx.x;
  const int L = tid & 63;
  const int w = tid >> 6;
  const int g = L >> 4;
  const int c = L & 15;

  __shared__ __align__(16) short Bs[16384];       // swizzled W2^T; aliased post-barrier
  __shared__ __align__(16) float baseA[H];        // affine layer-1 SoA
  __shared__ __align__(16) float slopeA[H];
  __shared__ float ts_s[T];
  __shared__ float mask_s[T];
  __shared__ float wred[2][4];
  __shared__ float wtot[2];

  // per-ray scalars (wave-uniform -> scalar loads; written by preprocess)
  const float tfar_c = rayp_all[ray*8+0];
  const float dnorm  = rayp_all[ray*8+1];
  const float actf   = rayp_all[ray*8+2];
  const float cpo0   = rayp_all[ray*8+3];
  const float cpo1   = rayp_all[ray*8+4];
  const float cpo2   = rayp_all[ray*8+5];
  const float tnear  = rayp_all[ray*8+6];

  // ---- stage W2 (LDS), proven float4 path ----
  {
    const float4* src = (const float4*)w2t;
    float4* dst = (float4*)Bs;
    #pragma unroll
    for (int i = 0; i < 8; ++i) dst[tid + i * 256] = src[tid + i * 256];
  }

  // ---- per-sample setup (tid<128): samples + affine layer-1 coefficients ----
  if (tid < T) {
    const int tl = tid;
    const float ox = origins[ray*3+0], oy = origins[ray*3+1], oz = origins[ray*3+2];
    const float dx = dirs[ray*3+0],  dy = dirs[ray*3+1],  dz = dirs[ray*3+2];
    const bool active = actf != 0.f;
    const float ut = u[ray*T + tl];
    const float frac = ((float)tl + ut) * (1.f/(float)T);
    const float tt = tnear + (tfar_c - tnear) * frac;
    const float px = fmaf(dx, tt, ox);
    const float py = fmaf(dy, tt, oy);
    const float pz = fmaf(dz, tt, oz);
    ts_s[tl] = tt;
    const bool m = (fabsf(px) <= 1.f) && (fabsf(py) <= 1.f) && (fabsf(pz) <= 1.f) && active;
    mask_s[tl] = m ? 1.f : 0.f;
    const float w0 = W1[tl], w1v = W1[H + tl], w2v = W1[2*H + tl];
    baseA[tl]  = fmaf(ox, w0, fmaf(oy, w1v, fmaf(oz, w2v, b1[tl])));
    slopeA[tl] = fmaf(dx, w0, fmaf(dy, w1v, dz * w2v));
  }

  // ---- acc init = b2 (uniform global reads, L2-hot) ----
  f32x4 acc[2][8];
  #pragma unroll
  for (int mt = 0; mt < 8; ++mt) {
    const float4 bv = *(const float4*)&b2[mt*16 + g*4];
    #pragma unroll
    for (int tm = 0; tm < 2; ++tm) {
      acc[tm][mt][0] = bv.x; acc[tm][mt][1] = bv.y;
      acc[tm][mt][2] = bv.z; acc[tm][mt][3] = bv.w;
    }
  }
  __syncthreads();

  // ---- fused affine-layer1 (packed VALU) + layer2 (MFMA, W2 frags from LDS) ----
  const float t0 = ts_s[32*w + c];
  const float t1 = ts_s[32*w + 16 + c];
  const f32x2 tz0 = {t0, t0}, tz1 = {t1, t1};
  const f32x2 zero2 = {0.f, 0.f};

  #pragma unroll
  for (int ks = 0; ks < 4; ++ks) {
    const int kb = ks*32 + g*8;
    const f32x4 bq0 = *(const f32x4*)&baseA[kb];
    const f32x4 bq1 = *(const f32x4*)&baseA[kb+4];
    const f32x4 sq0 = *(const f32x4*)&slopeA[kb];
    const f32x4 sq1 = *(const f32x4*)&slopeA[kb+4];
    const f32x2 b01 = {bq0[0], bq0[1]}, b23 = {bq0[2], bq0[3]};
    const f32x2 b45 = {bq1[0], bq1[1]}, b67 = {bq1[2], bq1[3]};
    const f32x2 s01 = {sq0[0], sq0[1]}, s23 = {sq0[2], sq0[3]};
    const f32x2 s45 = {sq1[0], sq1[1]}, s67 = {sq1[2], sq1[3]};
    const f32x2 a01 = __builtin_elementwise_max(__builtin_elementwise_fma(tz0, s01, b01), zero2);
    const f32x2 a23 = __builtin_elementwise_max(__builtin_elementwise_fma(tz0, s23, b23), zero2);
    const f32x2 a45 = __builtin_elementwise_max(__builtin_elementwise_fma(tz0, s45, b45), zero2);
    const f32x2 a67 = __builtin_elementwise_max(__builtin_elementwise_fma(tz0, s67, b67), zero2);
    const f32x2 e01 = __builtin_elementwise_max(__builtin_elementwise_fma(tz1, s01, b01), zero2);
    const f32x2 e23 = __builtin_elementwise_max(__builtin_elementwise_fma(tz1, s23, b23), zero2);
    const f32x2 e45 = __builtin_elementwise_max(__builtin_elementwise_fma(tz1, s45, b45), zero2);
    const f32x2 e67 = __builtin_elementwise_max(__builtin_elementwise_fma(tz1, s67, b67), zero2);
    union U { uint4 u; short8 s; } A0, A1;
    A0.u = make_uint4(pk2(a01), pk2(a23), pk2(a45), pk2(a67));
    A1.u = make_uint4(pk2(e01), pk2(e23), pk2(e45), pk2(e67));
    const int swb = ((ks*4 + g) ^ (c & 7)) * 8;   // swizzled octet (conflict-free)
    #pragma unroll
    for (int mt = 0; mt < 8; ++mt) {
      const short8 wf = *(const short8*)&Bs[(mt*16 + c)*128 + swb];
      acc[0][mt] = __builtin_amdgcn_mfma_f32_16x16x32_bf16(wf, A0.s, acc[0][mt], 0, 0, 0);
      acc[1][mt] = __builtin_amdgcn_mfma_f32_16x16x32_bf16(wf, A1.s, acc[1][mt], 0, 0, 0);
    }
  }
  __syncthreads();   // all waves done with Bs -> safe to alias SredP/As2 onto it
  float4* SredP = (float4*)Bs;                // bytes [0, 2048)
  short*  As2   = Bs + 2048;                  // bytes [4096, 24576): per-wave per-kk slabs

  // ---- epilogue: relu -> bf16 slab (PER-KK DISJOINT) -> MFMA dot with Wout ----
  // Per wave: 4 kk x 640-short regions (2560 shorts = 5120 B). All 8 writes of
  // a tm issue before any read -> no WAR serialization through the LDS pipe.
  short* As2w = As2 + w * 2560;
  short8 wa[4];
  #pragma unroll
  for (int kk = 0; kk < 4; ++kk)
    wa[kk] = *(const short8*)&woutf[(kk*64 + L)*8];   // global, L2-hot

  #pragma unroll
  for (int tm = 0; tm < 2; ++tm) {
    // phase 1: all writes (independent, pipeline freely)
    #pragma unroll
    for (int kk = 0; kk < 4; ++kk) {
      #pragma unroll
      for (int i = 0; i < 2; ++i) {
        const f32x4 a = acc[tm][kk*2 + i];
        const f32x2 h01 = __builtin_elementwise_max((f32x2){a[0], a[1]}, zero2);
        const f32x2 h23 = __builtin_elementwise_max((f32x2){a[2], a[3]}, zero2);
        *(uint2*)&As2w[kk*640 + c*40 + i*16 + g*4] = make_uint2(pk2(h01), pk2(h23));
      }
    }
    // phase 2: reads + chained MFMA (reads all in flight; only oacc chains)
    f32x4 oacc;
    oacc[0] = 0.f; oacc[1] = 0.f; oacc[2] = 0.f; oacc[3] = 0.f;
    #pragma unroll
    for (int kk = 0; kk < 4; ++kk) {
      const short8 hbf = *(const short8*)&As2w[kk*640 + c*40 + g*8];
      oacc = __builtin_amdgcn_mfma_f32_16x16x32_bf16(wa[kk], hbf, oacc, 0, 0, 0);
    }
    if (g == 0)   // lane holds {sigma,c0,c1,c2} for sample 32w+16tm+c
      SredP[32*w + 16*tm + c] = make_float4(oacc[0], oacc[1], oacc[2], oacc[3]);
  }
  __syncthreads();

  // ---- per-sample activations + transmittance (tid<128) ----
  float sd = 0.f, cc0 = 0.f, cc1 = 0.f, cc2 = 0.f;
  if (tid < T) {
    const float4 sv = SredP[tid];
    const float mk = mask_s[tid];
    const float sigma = softplus_f(sv.x + bd[0]) * mk;
    cc0 = mk * sigmoid_f(sv.y + cpo0);
    cc1 = mk * sigmoid_f(sv.z + cpo1);
    cc2 = mk * sigmoid_f(sv.w + cpo2);
    const float tt = ts_s[tid];
    const float tnext = (tid < T-1) ? ts_s[tid + 1] : tfar_c * 10.f;
    sd = sigma * (tnext - tt) * dnorm;
  }

  // ---- inclusive scan: in-wave shfl + cross-wave stitch ----
  float val = sd;
  #pragma unroll
  for (int off = 1; off < 64; off <<= 1) {
    const float tmp = __shfl_up(val, off);
    if (L >= off) val += tmp;
  }
  if (tid < T && L == 63) wtot[w] = val;
  __syncthreads();
  const float csum = val + ((w == 1) ? wtot[0] : 0.f);

  // ---- weights + per-ray reduction ----
  float wgt = 0.f, wcx = 0.f, wcy = 0.f, wcz = 0.f;
  if (tid < T) {
    wgt = fexp(sd - csum) - fexp(-csum);
    wcx = wgt * cc0; wcy = wgt * cc1; wcz = wgt * cc2;
  }
  #pragma unroll
  for (int mm = 32; mm >= 1; mm >>= 1) {
    wgt += __shfl_xor(wgt, mm);
    wcx += __shfl_xor(wcx, mm);
    wcy += __shfl_xor(wcy, mm);
    wcz += __shfl_xor(wcz, mm);
  }
  if (tid < T && L == 0) {
    wred[w][0] = wgt; wred[w][1] = wcx; wred[w][2] = wcy; wred[w][3] = wcz;
  }
  __syncthreads();
  if (tid == 0) {
    const float aw = wred[0][0] + wred[1][0];
    const float o0 = wred[0][1] + wred[1][1];
    const float o1 = wred[0][2] + wred[1][2];
    const float o2 = wred[0][3] + wred[1][3];
    const bool act = actf != 0.f;
    out[ray*4+0] = act ? o0 : 0.f;
    out[ray*4+1] = act ? o1 : 0.f;
    out[ray*4+2] = act ? o2 : 0.f;
    out[ray*4+3] = act ? aw : 0.f;
  }
}

extern "C" void kernel_launch(void* const* d_in, const int* in_sizes, int n_in,
                              void* d_out, int out_size, void* d_ws, size_t ws_size,
                              hipStream_t stream) {
  const float* origins = (const float*)d_in[0];
  const float* dirs    = (const float*)d_in[1];
  const float* u       = (const float*)d_in[2];
  const float* W1      = (const float*)d_in[3];
  const float* b1      = (const float*)d_in[4];
  const float* W2      = (const float*)d_in[5];
  const float* b2      = (const float*)d_in[6];
  const float* Wd      = (const float*)d_in[7];
  const float* bd      = (const float*)d_in[8];
  const float* Wc      = (const float*)d_in[9];
  const float* bc      = (const float*)d_in[10];

  unsigned short* w2t      = (unsigned short*)d_ws;
  unsigned short* woutf    = (unsigned short*)((char*)d_ws + 32768);
  float*          rayp_all = (float*)((char*)d_ws + 36864);

  preprocess<<<64, 256, 0, stream>>>(W2, Wd, Wc, bc, origins, dirs,
                                     w2t, woutf, rayp_all);
  nerf_render<<<NRAYS, 256, 0, stream>>>(origins, dirs, u, W1, b1, b2, bd,
                                         w2t, woutf, rayp_all, (float*)d_out);
}